// Round 1
// baseline (2527.861 us; speedup 1.0000x reference)
//
#include <hip/hip_runtime.h>

#define EPS 1e-5f

__device__ __forceinline__ float waveReduceSum(float v) {
    #pragma unroll
    for (int off = 32; off > 0; off >>= 1)
        v += __shfl_down(v, off, 64);
    return v;
}

// ---------------- K1: sparse conv1 (C=1 -> 8) + BN-stat accumulation ----------------
__global__ void k_conv1(const float* __restrict__ f0, const float* __restrict__ W1,
                        const float* __restrict__ b1, const int* __restrict__ nbr0,
                        float* __restrict__ x1, float* __restrict__ stats, int n0) {
    __shared__ float sW[72];
    int t = threadIdx.x;
    if (t < 72) sW[t] = W1[t];
    __syncthreads();

    int n = blockIdx.x * blockDim.x + t;
    bool valid = (n < n0);
    float acc[8];
    if (valid) {
        #pragma unroll
        for (int c = 0; c < 8; ++c) acc[c] = b1[c];
        #pragma unroll
        for (int k = 0; k < 9; ++k) {
            int j = nbr0[(size_t)n * 9 + k];
            if (j >= 0) {
                float v = f0[j];
                #pragma unroll
                for (int c = 0; c < 8; ++c) acc[c] = fmaf(v, sW[k * 8 + c], acc[c]);
            }
        }
        float4 lo = {acc[0], acc[1], acc[2], acc[3]};
        float4 hi = {acc[4], acc[5], acc[6], acc[7]};
        float4* dst = (float4*)(x1 + (size_t)n * 8);
        dst[0] = lo; dst[1] = hi;
    } else {
        #pragma unroll
        for (int c = 0; c < 8; ++c) acc[c] = 0.f;
    }

    #pragma unroll
    for (int c = 0; c < 8; ++c) {
        float s = waveReduceSum(valid ? acc[c] : 0.f);
        float q = waveReduceSum(valid ? acc[c] * acc[c] : 0.f);
        if ((t & 63) == 0) {
            atomicAdd(&stats[c], s);
            atomicAdd(&stats[8 + c], q);
        }
    }
}

// ---------------- K2: BN1+ReLU fused into 2x2 max pool ----------------
__global__ void k_pool1(const float* __restrict__ x1, const int* __restrict__ pmap1,
                        const float* __restrict__ stats, const float* __restrict__ gamma1,
                        const float* __restrict__ beta1, float* __restrict__ p1,
                        int n1, float invn) {
    int i = blockIdx.x * blockDim.x + threadIdx.x;
    if (i >= n1) return;
    float m[8], sc[8], bb[8];
    #pragma unroll
    for (int c = 0; c < 8; ++c) {
        float mu  = stats[c] * invn;
        float var = stats[8 + c] * invn - mu * mu;
        m[c]  = mu;
        sc[c] = rsqrtf(var + EPS) * gamma1[c];
        bb[c] = beta1[c];
    }
    float best[8];
    #pragma unroll
    for (int c = 0; c < 8; ++c) best[c] = 0.f;  // relu outputs are >= 0 and >=1 child exists
    #pragma unroll
    for (int k = 0; k < 4; ++k) {
        int j = pmap1[(size_t)i * 4 + k];
        if (j >= 0) {
            const float4* src = (const float4*)(x1 + (size_t)j * 8);
            float4 lo = src[0], hi = src[1];
            float v[8] = {lo.x, lo.y, lo.z, lo.w, hi.x, hi.y, hi.z, hi.w};
            #pragma unroll
            for (int c = 0; c < 8; ++c) {
                float z = fmaxf(fmaf(v[c] - m[c], sc[c], bb[c]), 0.f);
                best[c] = fmaxf(best[c], z);
            }
        }
    }
    float4 lo = {best[0], best[1], best[2], best[3]};
    float4 hi = {best[4], best[5], best[6], best[7]};
    float4* dst = (float4*)(p1 + (size_t)i * 8);
    dst[0] = lo; dst[1] = hi;
}

// ---------------- K3: sparse conv2 (8 -> 16) + BN-stat accumulation ----------------
__global__ void k_conv2(const float* __restrict__ p1, const float* __restrict__ W2,
                        const float* __restrict__ b2, const int* __restrict__ nbr1,
                        float* __restrict__ x2, float* __restrict__ stats, int n1) {
    __shared__ float sW[1152];
    for (int t = threadIdx.x; t < 1152; t += blockDim.x) sW[t] = W2[t];
    __syncthreads();

    int n = blockIdx.x * blockDim.x + threadIdx.x;
    bool valid = (n < n1);
    float acc[16];
    if (valid) {
        #pragma unroll
        for (int c = 0; c < 16; ++c) acc[c] = b2[c];
        #pragma unroll
        for (int k = 0; k < 9; ++k) {
            int j = nbr1[(size_t)n * 9 + k];
            if (j >= 0) {
                const float4* src = (const float4*)(p1 + (size_t)j * 8);
                float4 lo = src[0], hi = src[1];
                float g[8] = {lo.x, lo.y, lo.z, lo.w, hi.x, hi.y, hi.z, hi.w};
                #pragma unroll
                for (int ci = 0; ci < 8; ++ci) {
                    const float* w = &sW[(k * 8 + ci) * 16];
                    #pragma unroll
                    for (int c = 0; c < 16; ++c) acc[c] = fmaf(g[ci], w[c], acc[c]);
                }
            }
        }
        float4* dst = (float4*)(x2 + (size_t)n * 16);
        #pragma unroll
        for (int q4 = 0; q4 < 4; ++q4) {
            float4 v = {acc[q4 * 4], acc[q4 * 4 + 1], acc[q4 * 4 + 2], acc[q4 * 4 + 3]};
            dst[q4] = v;
        }
    } else {
        #pragma unroll
        for (int c = 0; c < 16; ++c) acc[c] = 0.f;
    }

    #pragma unroll
    for (int c = 0; c < 16; ++c) {
        float s = waveReduceSum(valid ? acc[c] : 0.f);
        float q = waveReduceSum(valid ? acc[c] * acc[c] : 0.f);
        if ((threadIdx.x & 63) == 0) {
            atomicAdd(&stats[16 + c], s);
            atomicAdd(&stats[32 + c], q);
        }
    }
}

// ---------------- K4: BN2+ReLU fused into pool + FC(16->2) ----------------
__global__ void k_pool2_fc(const float* __restrict__ x2, const int* __restrict__ pmap2,
                           const float* __restrict__ stats, const float* __restrict__ gamma2,
                           const float* __restrict__ beta2, const float* __restrict__ Wfc,
                           const float* __restrict__ bfc, float* __restrict__ out,
                           int n2, float invn) {
    int i = blockIdx.x * blockDim.x + threadIdx.x;
    if (i >= n2) return;
    float m[16], sc[16], bb[16];
    #pragma unroll
    for (int c = 0; c < 16; ++c) {
        float mu  = stats[16 + c] * invn;
        float var = stats[32 + c] * invn - mu * mu;
        m[c]  = mu;
        sc[c] = rsqrtf(var + EPS) * gamma2[c];
        bb[c] = beta2[c];
    }
    float best[16];
    #pragma unroll
    for (int c = 0; c < 16; ++c) best[c] = 0.f;
    #pragma unroll
    for (int k = 0; k < 4; ++k) {
        int j = pmap2[(size_t)i * 4 + k];
        if (j >= 0) {
            const float4* src = (const float4*)(x2 + (size_t)j * 16);
            #pragma unroll
            for (int q4 = 0; q4 < 4; ++q4) {
                float4 v4 = src[q4];
                float v[4] = {v4.x, v4.y, v4.z, v4.w};
                #pragma unroll
                for (int c = 0; c < 4; ++c) {
                    int cc = q4 * 4 + c;
                    float z = fmaxf(fmaf(v[c] - m[cc], sc[cc], bb[cc]), 0.f);
                    best[cc] = fmaxf(best[cc], z);
                }
            }
        }
    }
    float o0 = bfc[0], o1 = bfc[1];
    #pragma unroll
    for (int c = 0; c < 16; ++c) {
        o0 = fmaf(best[c], Wfc[c * 2 + 0], o0);
        o1 = fmaf(best[c], Wfc[c * 2 + 1], o1);
    }
    out[(size_t)i * 2 + 0] = o0;
    out[(size_t)i * 2 + 1] = o1;
}

extern "C" void kernel_launch(void* const* d_in, const int* in_sizes, int n_in,
                              void* d_out, int out_size, void* d_ws, size_t ws_size,
                              hipStream_t stream) {
    const float* f0     = (const float*)d_in[0];
    const float* W1     = (const float*)d_in[1];
    const float* b1     = (const float*)d_in[2];
    const float* gamma1 = (const float*)d_in[3];
    const float* beta1  = (const float*)d_in[4];
    const float* W2     = (const float*)d_in[5];
    const float* b2     = (const float*)d_in[6];
    const float* gamma2 = (const float*)d_in[7];
    const float* beta2  = (const float*)d_in[8];
    const float* Wfc    = (const float*)d_in[9];
    const float* bfc    = (const float*)d_in[10];
    const int*   nbr0   = (const int*)d_in[11];
    const int*   pmap1  = (const int*)d_in[12];
    const int*   nbr1   = (const int*)d_in[13];
    const int*   pmap2  = (const int*)d_in[14];

    const int n0 = in_sizes[0];
    const int n1 = in_sizes[12] / 4;
    const int n2 = in_sizes[14] / 4;

    float* ws    = (float*)d_ws;
    float* stats = ws;                       // 48 floats used, pad to 64
    float* x1    = ws + 64;                  // n0*8
    float* p1    = x1 + (size_t)n0 * 8;      // n1*8
    float* x2    = p1 + (size_t)n1 * 8;      // n1*16

    hipMemsetAsync(stats, 0, 64 * sizeof(float), stream);

    const int B = 256;
    k_conv1<<<(n0 + B - 1) / B, B, 0, stream>>>(f0, W1, b1, nbr0, x1, stats, n0);
    k_pool1<<<(n1 + B - 1) / B, B, 0, stream>>>(x1, pmap1, stats, gamma1, beta1, p1,
                                                n1, 1.0f / (float)n0);
    k_conv2<<<(n1 + B - 1) / B, B, 0, stream>>>(p1, W2, b2, nbr1, x2, stats, n1);
    k_pool2_fc<<<(n2 + B - 1) / B, B, 0, stream>>>(x2, pmap2, stats, gamma2, beta2,
                                                   Wfc, bfc, (float*)d_out,
                                                   n2, 1.0f / (float)n1);
}

// Round 2
// 87.986 us; speedup vs baseline: 28.7303x; 28.7303x over previous
//
#include <hip/hip_runtime.h>

#define EPS 1e-5f
#define NSLOT 64   // spread-slot copies of the stats accumulators (64 floats each)

__device__ __forceinline__ float waveReduceSum(float v) {
    #pragma unroll
    for (int off = 32; off > 0; off >>= 1)
        v += __shfl_down(v, off, 64);
    return v;
}

// ---------------- K1: sparse conv1 (C=1 -> 8) + per-block BN-stat partials ----------------
__global__ void k_conv1(const float* __restrict__ f0, const float* __restrict__ W1,
                        const float* __restrict__ b1, const int* __restrict__ nbr0,
                        float* __restrict__ x1, float* __restrict__ slots, int n0) {
    __shared__ float sW[72];
    __shared__ float sred[16];
    int t = threadIdx.x;
    if (t < 72) sW[t] = W1[t];
    if (t < 16) sred[t] = 0.f;
    __syncthreads();

    int n = blockIdx.x * blockDim.x + t;
    bool valid = (n < n0);
    float acc[8];
    if (valid) {
        #pragma unroll
        for (int c = 0; c < 8; ++c) acc[c] = b1[c];
        #pragma unroll
        for (int k = 0; k < 9; ++k) {
            int j = nbr0[(size_t)n * 9 + k];
            if (j >= 0) {
                float v = f0[j];
                #pragma unroll
                for (int c = 0; c < 8; ++c) acc[c] = fmaf(v, sW[k * 8 + c], acc[c]);
            }
        }
        float4 lo = {acc[0], acc[1], acc[2], acc[3]};
        float4 hi = {acc[4], acc[5], acc[6], acc[7]};
        float4* dst = (float4*)(x1 + (size_t)n * 8);
        dst[0] = lo; dst[1] = hi;
    } else {
        #pragma unroll
        for (int c = 0; c < 8; ++c) acc[c] = 0.f;
    }

    // wave reduce -> LDS block reduce
    #pragma unroll
    for (int c = 0; c < 8; ++c) {
        float s = waveReduceSum(acc[c]);
        float q = waveReduceSum(acc[c] * acc[c]);
        if ((t & 63) == 0) {
            atomicAdd(&sred[c], s);
            atomicAdd(&sred[8 + c], q);
        }
    }
    __syncthreads();
    // one global atomic per channel per block, spread over NSLOT slot copies
    if (t < 16) {
        float* slot = slots + (size_t)(blockIdx.x & (NSLOT - 1)) * 64;
        atomicAdd(&slot[t], sred[t]);
    }
}

// ---------------- finalize: collapse NSLOT slot copies into final stats ----------------
__global__ void k_finalize(const float* __restrict__ slots, float* __restrict__ stats,
                           int base, int cnt) {
    int c = threadIdx.x;
    if (c >= cnt) return;
    float s = 0.f;
    #pragma unroll 8
    for (int k = 0; k < NSLOT; ++k) s += slots[(size_t)k * 64 + base + c];
    stats[base + c] = s;
}

// ---------------- K2: BN1+ReLU fused into 2x2 max pool ----------------
__global__ void k_pool1(const float* __restrict__ x1, const int* __restrict__ pmap1,
                        const float* __restrict__ stats, const float* __restrict__ gamma1,
                        const float* __restrict__ beta1, float* __restrict__ p1,
                        int n1, float invn) {
    int i = blockIdx.x * blockDim.x + threadIdx.x;
    if (i >= n1) return;
    float m[8], sc[8], bb[8];
    #pragma unroll
    for (int c = 0; c < 8; ++c) {
        float mu  = stats[c] * invn;
        float var = stats[8 + c] * invn - mu * mu;
        m[c]  = mu;
        sc[c] = rsqrtf(var + EPS) * gamma1[c];
        bb[c] = beta1[c];
    }
    float best[8];
    #pragma unroll
    for (int c = 0; c < 8; ++c) best[c] = 0.f;  // relu outputs >= 0, >=1 child exists
    #pragma unroll
    for (int k = 0; k < 4; ++k) {
        int j = pmap1[(size_t)i * 4 + k];
        if (j >= 0) {
            const float4* src = (const float4*)(x1 + (size_t)j * 8);
            float4 lo = src[0], hi = src[1];
            float v[8] = {lo.x, lo.y, lo.z, lo.w, hi.x, hi.y, hi.z, hi.w};
            #pragma unroll
            for (int c = 0; c < 8; ++c) {
                float z = fmaxf(fmaf(v[c] - m[c], sc[c], bb[c]), 0.f);
                best[c] = fmaxf(best[c], z);
            }
        }
    }
    float4 lo = {best[0], best[1], best[2], best[3]};
    float4 hi = {best[4], best[5], best[6], best[7]};
    float4* dst = (float4*)(p1 + (size_t)i * 8);
    dst[0] = lo; dst[1] = hi;
}

// ---------------- K3: sparse conv2 (8 -> 16) + per-block BN-stat partials ----------------
__global__ void k_conv2(const float* __restrict__ p1, const float* __restrict__ W2,
                        const float* __restrict__ b2, const int* __restrict__ nbr1,
                        float* __restrict__ x2, float* __restrict__ slots, int n1) {
    __shared__ float sW[1152];
    __shared__ float sred[32];
    for (int t = threadIdx.x; t < 1152; t += blockDim.x) sW[t] = W2[t];
    if (threadIdx.x < 32) sred[threadIdx.x] = 0.f;
    __syncthreads();

    int n = blockIdx.x * blockDim.x + threadIdx.x;
    bool valid = (n < n1);
    float acc[16];
    if (valid) {
        #pragma unroll
        for (int c = 0; c < 16; ++c) acc[c] = b2[c];
        #pragma unroll
        for (int k = 0; k < 9; ++k) {
            int j = nbr1[(size_t)n * 9 + k];
            if (j >= 0) {
                const float4* src = (const float4*)(p1 + (size_t)j * 8);
                float4 lo = src[0], hi = src[1];
                float g[8] = {lo.x, lo.y, lo.z, lo.w, hi.x, hi.y, hi.z, hi.w};
                #pragma unroll
                for (int ci = 0; ci < 8; ++ci) {
                    const float* w = &sW[(k * 8 + ci) * 16];
                    #pragma unroll
                    for (int c = 0; c < 16; ++c) acc[c] = fmaf(g[ci], w[c], acc[c]);
                }
            }
        }
        float4* dst = (float4*)(x2 + (size_t)n * 16);
        #pragma unroll
        for (int q4 = 0; q4 < 4; ++q4) {
            float4 v = {acc[q4 * 4], acc[q4 * 4 + 1], acc[q4 * 4 + 2], acc[q4 * 4 + 3]};
            dst[q4] = v;
        }
    } else {
        #pragma unroll
        for (int c = 0; c < 16; ++c) acc[c] = 0.f;
    }

    #pragma unroll
    for (int c = 0; c < 16; ++c) {
        float s = waveReduceSum(acc[c]);
        float q = waveReduceSum(acc[c] * acc[c]);
        if ((threadIdx.x & 63) == 0) {
            atomicAdd(&sred[c], s);
            atomicAdd(&sred[16 + c], q);
        }
    }
    __syncthreads();
    if (threadIdx.x < 32) {
        float* slot = slots + (size_t)(blockIdx.x & (NSLOT - 1)) * 64;
        atomicAdd(&slot[16 + threadIdx.x], sred[threadIdx.x]);
    }
}

// ---------------- K4: BN2+ReLU fused into pool + FC(16->2) ----------------
__global__ void k_pool2_fc(const float* __restrict__ x2, const int* __restrict__ pmap2,
                           const float* __restrict__ stats, const float* __restrict__ gamma2,
                           const float* __restrict__ beta2, const float* __restrict__ Wfc,
                           const float* __restrict__ bfc, float* __restrict__ out,
                           int n2, float invn) {
    int i = blockIdx.x * blockDim.x + threadIdx.x;
    if (i >= n2) return;
    float m[16], sc[16], bb[16];
    #pragma unroll
    for (int c = 0; c < 16; ++c) {
        float mu  = stats[16 + c] * invn;
        float var = stats[32 + c] * invn - mu * mu;
        m[c]  = mu;
        sc[c] = rsqrtf(var + EPS) * gamma2[c];
        bb[c] = beta2[c];
    }
    float best[16];
    #pragma unroll
    for (int c = 0; c < 16; ++c) best[c] = 0.f;
    #pragma unroll
    for (int k = 0; k < 4; ++k) {
        int j = pmap2[(size_t)i * 4 + k];
        if (j >= 0) {
            const float4* src = (const float4*)(x2 + (size_t)j * 16);
            #pragma unroll
            for (int q4 = 0; q4 < 4; ++q4) {
                float4 v4 = src[q4];
                float v[4] = {v4.x, v4.y, v4.z, v4.w};
                #pragma unroll
                for (int c = 0; c < 4; ++c) {
                    int cc = q4 * 4 + c;
                    float z = fmaxf(fmaf(v[c] - m[cc], sc[cc], bb[cc]), 0.f);
                    best[cc] = fmaxf(best[cc], z);
                }
            }
        }
    }
    float o0 = bfc[0], o1 = bfc[1];
    #pragma unroll
    for (int c = 0; c < 16; ++c) {
        o0 = fmaf(best[c], Wfc[c * 2 + 0], o0);
        o1 = fmaf(best[c], Wfc[c * 2 + 1], o1);
    }
    out[(size_t)i * 2 + 0] = o0;
    out[(size_t)i * 2 + 1] = o1;
}

extern "C" void kernel_launch(void* const* d_in, const int* in_sizes, int n_in,
                              void* d_out, int out_size, void* d_ws, size_t ws_size,
                              hipStream_t stream) {
    const float* f0     = (const float*)d_in[0];
    const float* W1     = (const float*)d_in[1];
    const float* b1     = (const float*)d_in[2];
    const float* gamma1 = (const float*)d_in[3];
    const float* beta1  = (const float*)d_in[4];
    const float* W2     = (const float*)d_in[5];
    const float* b2     = (const float*)d_in[6];
    const float* gamma2 = (const float*)d_in[7];
    const float* beta2  = (const float*)d_in[8];
    const float* Wfc    = (const float*)d_in[9];
    const float* bfc    = (const float*)d_in[10];
    const int*   nbr0   = (const int*)d_in[11];
    const int*   pmap1  = (const int*)d_in[12];
    const int*   nbr1   = (const int*)d_in[13];
    const int*   pmap2  = (const int*)d_in[14];

    const int n0 = in_sizes[0];
    const int n1 = in_sizes[12] / 4;
    const int n2 = in_sizes[14] / 4;

    float* ws    = (float*)d_ws;
    float* slots = ws;                              // NSLOT * 64 floats
    float* stats = ws + (size_t)NSLOT * 64;         // 64 floats
    float* x1    = stats + 64;                      // n0*8
    float* p1    = x1 + (size_t)n0 * 8;             // n1*8
    float* x2    = p1 + (size_t)n1 * 8;             // n1*16

    hipMemsetAsync(slots, 0, ((size_t)NSLOT * 64 + 64) * sizeof(float), stream);

    const int B = 256;
    k_conv1<<<(n0 + B - 1) / B, B, 0, stream>>>(f0, W1, b1, nbr0, x1, slots, n0);
    k_finalize<<<1, 64, 0, stream>>>(slots, stats, 0, 16);
    k_pool1<<<(n1 + B - 1) / B, B, 0, stream>>>(x1, pmap1, stats, gamma1, beta1, p1,
                                                n1, 1.0f / (float)n0);
    k_conv2<<<(n1 + B - 1) / B, B, 0, stream>>>(p1, W2, b2, nbr1, x2, slots, n1);
    k_finalize<<<1, 64, 0, stream>>>(slots, stats, 16, 32);
    k_pool2_fc<<<(n2 + B - 1) / B, B, 0, stream>>>(x2, pmap2, stats, gamma2, beta2,
                                                   Wfc, bfc, (float*)d_out,
                                                   n2, 1.0f / (float)n1);
}